// Round 9
// baseline (331.474 us; speedup 1.0000x reference)
//
#include <hip/hip_runtime.h>
#include <stdint.h>

typedef unsigned short u16;
typedef __attribute__((ext_vector_type(8))) short short8;   // 8 bf16 = 4 VGPR
typedef __attribute__((ext_vector_type(4))) short s16x4;    // 4 bf16 = 2 VGPR
typedef __attribute__((ext_vector_type(4))) float f32x4;

#define MFMA16(a,b,c) __builtin_amdgcn_mfma_f32_16x16x32_bf16(a,b,c,0,0,0)

constexpr int B_ = 4, C_ = 512, N_ = 4096, D_ = 64;  // D_ = CQK = C/8

static __device__ __forceinline__ u16 f2bf(float f) {
    uint32_t u = __builtin_bit_cast(uint32_t, f);
    uint32_t r = (u + 0x7FFFu + ((u >> 16) & 1u)) >> 16;   // RNE
    return (u16)r;
}
static __device__ __forceinline__ float bf2f(u16 h) {
    return __builtin_bit_cast(float, (uint32_t)h << 16);
}

// ---------------- prep: Wcat bf16 [640][512] + biascat; Wq/bq pre-scaled by log2(e) ----
__global__ void prep_w(const float* Wq, const float* bq, const float* Wk, const float* bk,
                       const float* Wv, const float* bv, u16* Wcat, float* biascat) {
    const float LOG2E = 1.44269504088896340736f;
    int idx = blockIdx.x * 256 + threadIdx.x;
    if (idx < 640 * 512) {
        int row = idx >> 9, col = idx & 511;
        float w;
        if (row < 64)        w = Wq[row * 512 + col] * LOG2E;
        else if (row < 128)  w = Wk[(row - 64) * 512 + col];
        else                 w = Wv[(row - 128) * 512 + col];
        Wcat[idx] = f2bf(w);
    }
    if (idx < 640) {
        float bb;
        if (idx < 64)        bb = bq[idx] * LOG2E;
        else if (idx < 128)  bb = bk[idx - 64];
        else                 bb = bv[idx - 128];
        biascat[idx] = bb;
    }
}

// ---------------- transpose x [B][C][N] f32 -> xT [B][N][C] bf16 ----------------
__global__ void transpose_x(const float* __restrict__ x, u16* __restrict__ xT) {
    __shared__ float tile[32][33];
    int n0 = blockIdx.x * 32, c0 = blockIdx.y * 32, b = blockIdx.z;
    int tx = threadIdx.x & 31, ty = threadIdx.x >> 5;       // ty 0..7
    const float* xb = x + (size_t)b * C_ * N_;
#pragma unroll
    for (int r = 0; r < 4; r++) {
        int c = ty * 4 + r;
        tile[c][tx] = xb[(size_t)(c0 + c) * N_ + n0 + tx];
    }
    __syncthreads();
    u16* xTb = xT + (size_t)b * N_ * C_;
#pragma unroll
    for (int r = 0; r < 4; r++) {
        int n = ty * 4 + r;
        xTb[(size_t)(n0 + n) * C_ + c0 + tx] = f2bf(tile[tx][n]);
    }
}

// ---------------- projection GEMM: Y[640][4096] = Wcat x X_b^T, per batch --------
__global__ __launch_bounds__(256) void proj_gemm(const u16* __restrict__ Wcat,
                                                 const float* __restrict__ biascat,
                                                 const u16* __restrict__ xT,
                                                 u16* __restrict__ qT, u16* __restrict__ kT,
                                                 u16* __restrict__ v) {
    int b = blockIdx.z;
    int m0 = blockIdx.y * 64;
    int wave = threadIdx.x >> 6, lane = threadIdx.x & 63;
    int n0 = blockIdx.x * 256 + wave * 64;
    int lr = lane & 15, lc = lane >> 4;
    const u16* xTb = xT + (size_t)b * N_ * C_;

    f32x4 acc[4][4] = {};   // [ma][na]
    short8 aF[4], bF[4], aFn[4], bFn[4];
#pragma unroll
    for (int ma = 0; ma < 4; ma++)
        aF[ma] = *reinterpret_cast<const short8*>(&Wcat[(size_t)(m0 + ma * 16 + lr) * 512 + lc * 8]);
#pragma unroll
    for (int na = 0; na < 4; na++)
        bF[na] = *reinterpret_cast<const short8*>(&xTb[(size_t)(n0 + na * 16 + lr) * 512 + lc * 8]);

    for (int k0 = 0; k0 < 512; k0 += 32) {
        if (k0 < 480) {
            int kn = k0 + 32;
#pragma unroll
            for (int ma = 0; ma < 4; ma++)
                aFn[ma] = *reinterpret_cast<const short8*>(&Wcat[(size_t)(m0 + ma * 16 + lr) * 512 + kn + lc * 8]);
#pragma unroll
            for (int na = 0; na < 4; na++)
                bFn[na] = *reinterpret_cast<const short8*>(&xTb[(size_t)(n0 + na * 16 + lr) * 512 + kn + lc * 8]);
        }
#pragma unroll
        for (int ma = 0; ma < 4; ma++)
#pragma unroll
            for (int na = 0; na < 4; na++)
                acc[ma][na] = MFMA16(aF[ma], bF[na], acc[ma][na]);
#pragma unroll
        for (int t = 0; t < 4; t++) { aF[t] = aFn[t]; bF[t] = bFn[t]; }
    }
#pragma unroll
    for (int ma = 0; ma < 4; ma++) {
#pragma unroll
        for (int r = 0; r < 4; r++) {
            int m = m0 + ma * 16 + lc * 4 + r;
            float bias = biascat[m];
#pragma unroll
            for (int na = 0; na < 4; na++) {
                int n = n0 + na * 16 + lr;
                u16 hv = f2bf(acc[ma][na][r] + bias);
                if (m < 64)
                    qT[((size_t)b * N_ + n) * D_ + m] = hv;
                else if (m < 128)
                    kT[((size_t)b * N_ + n) * D_ + (m - 64)] = hv;
                else
                    v[((size_t)b * C_ + (m - 128)) * (size_t)N_ + n] = hv;
            }
        }
    }
}

// ---------------- fused attention, one pass, no max, SPLIT-J x2, register diet ----------------
// Grid 512 = (b, 64-i-tile, j-half), 8 waves. For TWO blocks/CU to be co-resident
// (the latency-hiding mechanism), TOTAL unified regs (VGPR+AGPR) must be <=128
// (R8: 88+64=152 -> 3 waves/SIMD -> only 1 block resident, 23% occ). Diet:
// Q lives in LDS (swizzled; staged once, read per-mt: 8 live regs, not 32);
// K single-buffered (8 regs). acc 64 AGPR + ~60 arch <= 128 -> (512,4) non-binding.
__global__ __launch_bounds__(512, 4) void attn(const u16* __restrict__ qT, const u16* __restrict__ kT,
                                               const u16* __restrict__ v,
                                               u16* __restrict__ Opart0, u16* __restrict__ Opart1,
                                               float* __restrict__ lpart) {
    int w = blockIdx.x;                 // [0,512)
    int xcd = w & 7, rest = w >> 3;     // rest in [0,64)
    int jh = rest & 1, slot = rest >> 1;
    int b = xcd >> 1;
    int i0 = (slot * 2 + (xcd & 1)) * 64;

    int wv = threadIdx.x >> 6, lane = threadIdx.x & 63;
    int lr = lane & 15, lc = lane >> 4;

    __shared__ u16 P_lds[2][64 * 128];  // 2 x 16KB, swizzled: byte = i*256 + (jb ^ ((i&7)<<4))
    __shared__ u16 Q_lds[64 * 64];      // 8KB, swizzled: byte = i*128 + (db ^ ((i&7)<<4))
    __shared__ float s_l[64][8];        // per-wave partial row sums

    const u16* qTb = qT + (size_t)b * N_ * D_;
    const u16* kTb = kT + (size_t)b * N_ * D_;
    const u16* vb  = v  + (size_t)b * C_ * N_;
    char* Qc = reinterpret_cast<char*>(Q_lds);

    // ---- stage Q (64i x 64d) into swizzled LDS, once ----
    {
        int i = threadIdx.x >> 3, ch = threadIdx.x & 7;
        short8 qv = *reinterpret_cast<const short8*>(&qTb[(size_t)(i0 + i) * D_ + ch * 8]);
        int byte_off = i * 128 + ((ch * 16) ^ ((i & 7) << 4));
        *reinterpret_cast<short8*>(Qc + byte_off) = qv;
    }

    f32x4 acc[4][4] = {};               // [mt][ct]: O slice 64 i x 64 c (unnormalized)
    float lsum[4] = {0.f, 0.f, 0.f, 0.f};

    __syncthreads();

    for (int t = 0; t < 16; t++) {
        int jt = jh * 16 + t;
        char* pb = reinterpret_cast<char*>(P_lds[t & 1]);

        // ---- K for this tile (single-buffer; stall covered by co-resident block) ----
        const u16* kp = kTb + (size_t)(jt * 128 + wv * 16 + lr) * D_;
        short8 kf0 = *reinterpret_cast<const short8*>(kp + lc * 8);
        short8 kf1 = *reinterpret_cast<const short8*>(kp + 32 + lc * 8);

        // ---- S phase: swapped mfma(K,Q): lane holds S'[i=mt*16+lr][j=wv*16+lc*4+r] ----
#pragma unroll
        for (int mt = 0; mt < 4; mt++) {
            int i = mt * 16 + lr;
            int qswz = (i & 7) << 4;
            short8 qf0 = *reinterpret_cast<const short8*>(Qc + i * 128 + ((lc * 16) ^ qswz));
            short8 qf1 = *reinterpret_cast<const short8*>(Qc + i * 128 + ((64 + lc * 16) ^ qswz));
            f32x4 s = {};
            s = MFMA16(kf0, qf0, s);
            s = MFMA16(kf1, qf1, s);
            s16x4 pk;
            float ps = 0.f;
#pragma unroll
            for (int r = 0; r < 4; r++) {
                float p = __builtin_amdgcn_exp2f(s[r]);   // exp(q.k): log2e folded into Wq
                ps += p;
                pk[r] = (short)f2bf(p);
            }
            lsum[mt] += ps;
            int byte_off = i * 256 + ((wv * 32 + lc * 8) ^ ((i & 7) << 4));
            *reinterpret_cast<s16x4*>(pb + byte_off) = pk;
        }

        // ---- barrier WITHOUT vmcnt drain: drain own LDS ops, then raw barrier ----
        asm volatile("s_waitcnt lgkmcnt(0)" ::: "memory");
        __builtin_amdgcn_s_barrier();
        __builtin_amdgcn_sched_barrier(0);

        // ---- PV phase: O[64 i][64 c] += P[64][128] * V[c][128 j]; V streamed at use ----
        __builtin_amdgcn_s_setprio(1);
#pragma unroll
        for (int kt = 0; kt < 4; kt++) {
            short8 pf[4];
#pragma unroll
            for (int mt = 0; mt < 4; mt++) {
                int i = mt * 16 + lr;
                int byte_off = i * 256 + (((kt * 64) + lc * 16) ^ ((i & 7) << 4));
                pf[mt] = *reinterpret_cast<const short8*>(pb + byte_off);
            }
#pragma unroll
            for (int ct = 0; ct < 4; ct++) {
                short8 vf = *reinterpret_cast<const short8*>(
                    &vb[(size_t)(wv * 64 + ct * 16 + lr) * N_ + jt * 128 + kt * 32 + lc * 8]);
#pragma unroll
                for (int mt = 0; mt < 4; mt++)
                    acc[mt][ct] = MFMA16(pf[mt], vf, acc[mt][ct]);
            }
        }
        __builtin_amdgcn_s_setprio(0);
    }

    // ---- row-sum reduce across lanes, then waves -> s_l ----
#pragma unroll
    for (int mt = 0; mt < 4; mt++) {
        float l_ = lsum[mt];
        l_ += __shfl_xor(l_, 16);
        l_ += __shfl_xor(l_, 32);
        if (lc == 0) s_l[mt * 16 + lr][wv] = l_;
    }
    __syncthreads();

    // ---- write partial l (wave 0, lanes 0-63) ----
    if (threadIdx.x < 64) {
        int i = threadIdx.x;
        float l = 0.f;
#pragma unroll
        for (int w2 = 0; w2 < 8; w2++) l += s_l[i][w2];
        lpart[((size_t)jh * B_ + b) * N_ + i0 + i] = l;
    }

    // ---- write partial O (unnormalized, bf16) ----
    u16* Op = (jh ? Opart1 : Opart0) + ((size_t)b * C_) * N_;
#pragma unroll
    for (int mt = 0; mt < 4; mt++)
#pragma unroll
        for (int ct = 0; ct < 4; ct++) {
            int c = wv * 64 + ct * 16 + lr;
            size_t off = (size_t)c * N_ + i0 + mt * 16 + lc * 4;
            ushort4 pk;
            pk.x = f2bf(acc[mt][ct][0]);
            pk.y = f2bf(acc[mt][ct][1]);
            pk.z = f2bf(acc[mt][ct][2]);
            pk.w = f2bf(acc[mt][ct][3]);
            *reinterpret_cast<ushort4*>(&Op[off]) = pk;
        }
}

// ---------------- reduce: out = gamma * (O0+O1)/(l0+l1) + x ----------------
__global__ __launch_bounds__(256) void reduce_out(const u16* __restrict__ O0, const u16* __restrict__ O1,
                                                  const float* __restrict__ lpart,
                                                  const float* __restrict__ x,
                                                  const float* __restrict__ gamma_p,
                                                  float* __restrict__ out) {
    int idx = blockIdx.x * 256 + threadIdx.x;        // [0, B*C*N/4)
    const int NQ = N_ / 4;                            // 1024
    int b = idx / (C_ * NQ);
    int rem = idx - b * (C_ * NQ);
    int c = rem / NQ;
    int i4 = (rem - c * NQ) * 4;

    size_t lo = (size_t)b * N_ + i4;
    float4 l0 = *reinterpret_cast<const float4*>(&lpart[lo]);
    float4 l1 = *reinterpret_cast<const float4*>(&lpart[(size_t)B_ * N_ + lo]);

    size_t oo = ((size_t)b * C_ + c) * N_ + i4;
    ushort4 a0 = *reinterpret_cast<const ushort4*>(&O0[oo]);
    ushort4 a1 = *reinterpret_cast<const ushort4*>(&O1[oo]);
    float4 xv = *reinterpret_cast<const float4*>(&x[oo]);
    float g = gamma_p[0];

    float4 ov;
    ov.x = g * ((bf2f(a0.x) + bf2f(a1.x)) / (l0.x + l1.x)) + xv.x;
    ov.y = g * ((bf2f(a0.y) + bf2f(a1.y)) / (l0.y + l1.y)) + xv.y;
    ov.z = g * ((bf2f(a0.z) + bf2f(a1.z)) / (l0.z + l1.z)) + xv.z;
    ov.w = g * ((bf2f(a0.w) + bf2f(a1.w)) / (l0.w + l1.w)) + xv.w;
    *reinterpret_cast<float4*>(&out[oo]) = ov;
}

extern "C" void kernel_launch(void* const* d_in, const int* in_sizes, int n_in,
                              void* d_out, int out_size, void* d_ws, size_t ws_size,
                              hipStream_t stream) {
    const float* x     = (const float*)d_in[0];
    const float* Wq    = (const float*)d_in[1];
    const float* bq    = (const float*)d_in[2];
    const float* Wk    = (const float*)d_in[3];
    const float* bk    = (const float*)d_in[4];
    const float* Wv    = (const float*)d_in[5];
    const float* bv    = (const float*)d_in[6];
    const float* gamma = (const float*)d_in[7];
    float* out = (float*)d_out;

    char* ws = (char*)d_ws;
    // layout (bytes): xT 16MB (aliased by Opart0 after proj) | Wcat 640KB | biascat 4KB |
    //                 qT 2MB | kT 2MB | v 16MB | Opart1 16MB | lpart 128KB  (~54.6MB)
    u16*   xT      = (u16*)ws;
    u16*   Wcat    = (u16*)(ws + (size_t)16777216);
    float* biascat = (float*)(ws + (size_t)16777216 + 655360);
    u16*   qT      = (u16*)(ws + (size_t)16777216 + 655360 + 4096);
    u16*   kT      = qT + (size_t)B_ * N_ * D_;
    u16*   v       = kT + (size_t)B_ * N_ * D_;
    u16*   Opart0  = (u16*)ws;                            // aliases xT (dead after proj_gemm)
    u16*   Opart1  = v + (size_t)B_ * C_ * N_;
    float* lpart   = (float*)(Opart1 + (size_t)B_ * C_ * N_);

    prep_w<<<1280, 256, 0, stream>>>(Wq, bq, Wk, bk, Wv, bv, Wcat, biascat);
    transpose_x<<<dim3(N_ / 32, C_ / 32, B_), 256, 0, stream>>>(x, xT);
    proj_gemm<<<dim3(N_ / 256, 640 / 64, B_), 256, 0, stream>>>(Wcat, biascat, xT, qT, kT, v);
    attn<<<512, 512, 0, stream>>>(qT, kT, v, Opart0, Opart1, lpart);
    reduce_out<<<(B_ * C_ * N_ / 4) / 256, 256, 0, stream>>>(Opart0, Opart1, lpart, x, gamma, out);
}

// Round 10
// 232.065 us; speedup vs baseline: 1.4284x; 1.4284x over previous
//
#include <hip/hip_runtime.h>
#include <stdint.h>

typedef unsigned short u16;
typedef __attribute__((ext_vector_type(8))) short short8;   // 8 bf16 = 4 VGPR
typedef __attribute__((ext_vector_type(4))) short s16x4;    // 4 bf16 = 2 VGPR
typedef __attribute__((ext_vector_type(4))) float f32x4;

#define MFMA16(a,b,c) __builtin_amdgcn_mfma_f32_16x16x32_bf16(a,b,c,0,0,0)

constexpr int B_ = 4, C_ = 512, N_ = 4096, D_ = 64;  // D_ = CQK = C/8

static __device__ __forceinline__ u16 f2bf(float f) {
    uint32_t u = __builtin_bit_cast(uint32_t, f);
    uint32_t r = (u + 0x7FFFu + ((u >> 16) & 1u)) >> 16;   // RNE
    return (u16)r;
}

// ---------------- prep: Wcat bf16 [640][512] + biascat; Wq/bq pre-scaled by log2(e) ----
__global__ void prep_w(const float* Wq, const float* bq, const float* Wk, const float* bk,
                       const float* Wv, const float* bv, u16* Wcat, float* biascat) {
    const float LOG2E = 1.44269504088896340736f;
    int idx = blockIdx.x * 256 + threadIdx.x;
    if (idx < 640 * 512) {
        int row = idx >> 9, col = idx & 511;
        float w;
        if (row < 64)        w = Wq[row * 512 + col] * LOG2E;
        else if (row < 128)  w = Wk[(row - 64) * 512 + col];
        else                 w = Wv[(row - 128) * 512 + col];
        Wcat[idx] = f2bf(w);
    }
    if (idx < 640) {
        float bb;
        if (idx < 64)        bb = bq[idx] * LOG2E;
        else if (idx < 128)  bb = bk[idx - 64];
        else                 bb = bv[idx - 128];
        biascat[idx] = bb;
    }
}

// ---------------- transpose x [B][C][N] f32 -> xT [B][N][C] bf16 ----------------
__global__ void transpose_x(const float* __restrict__ x, u16* __restrict__ xT) {
    __shared__ float tile[32][33];
    int n0 = blockIdx.x * 32, c0 = blockIdx.y * 32, b = blockIdx.z;
    int tx = threadIdx.x & 31, ty = threadIdx.x >> 5;       // ty 0..7
    const float* xb = x + (size_t)b * C_ * N_;
#pragma unroll
    for (int r = 0; r < 4; r++) {
        int c = ty * 4 + r;
        tile[c][tx] = xb[(size_t)(c0 + c) * N_ + n0 + tx];
    }
    __syncthreads();
    u16* xTb = xT + (size_t)b * N_ * C_;
#pragma unroll
    for (int r = 0; r < 4; r++) {
        int n = ty * 4 + r;
        xTb[(size_t)(n0 + n) * C_ + c0 + tx] = f2bf(tile[tx][n]);
    }
}

// ---------------- projection GEMM: Y[640][4096] = Wcat x X_b^T, per batch --------
__global__ __launch_bounds__(256) void proj_gemm(const u16* __restrict__ Wcat,
                                                 const float* __restrict__ biascat,
                                                 const u16* __restrict__ xT,
                                                 u16* __restrict__ qT, u16* __restrict__ kT,
                                                 u16* __restrict__ v) {
    int b = blockIdx.z;
    int m0 = blockIdx.y * 64;
    int wave = threadIdx.x >> 6, lane = threadIdx.x & 63;
    int n0 = blockIdx.x * 256 + wave * 64;
    int lr = lane & 15, lc = lane >> 4;
    const u16* xTb = xT + (size_t)b * N_ * C_;

    f32x4 acc[4][4] = {};   // [ma][na]
    short8 aF[4], bF[4], aFn[4], bFn[4];
#pragma unroll
    for (int ma = 0; ma < 4; ma++)
        aF[ma] = *reinterpret_cast<const short8*>(&Wcat[(size_t)(m0 + ma * 16 + lr) * 512 + lc * 8]);
#pragma unroll
    for (int na = 0; na < 4; na++)
        bF[na] = *reinterpret_cast<const short8*>(&xTb[(size_t)(n0 + na * 16 + lr) * 512 + lc * 8]);

    for (int k0 = 0; k0 < 512; k0 += 32) {
        if (k0 < 480) {
            int kn = k0 + 32;
#pragma unroll
            for (int ma = 0; ma < 4; ma++)
                aFn[ma] = *reinterpret_cast<const short8*>(&Wcat[(size_t)(m0 + ma * 16 + lr) * 512 + kn + lc * 8]);
#pragma unroll
            for (int na = 0; na < 4; na++)
                bFn[na] = *reinterpret_cast<const short8*>(&xTb[(size_t)(n0 + na * 16 + lr) * 512 + kn + lc * 8]);
        }
#pragma unroll
        for (int ma = 0; ma < 4; ma++)
#pragma unroll
            for (int na = 0; na < 4; na++)
                acc[ma][na] = MFMA16(aF[ma], bF[na], acc[ma][na]);
#pragma unroll
        for (int t = 0; t < 4; t++) { aF[t] = aFn[t]; bF[t] = bFn[t]; }
    }
#pragma unroll
    for (int ma = 0; ma < 4; ma++) {
#pragma unroll
        for (int r = 0; r < 4; r++) {
            int m = m0 + ma * 16 + lc * 4 + r;
            float bias = biascat[m];
#pragma unroll
            for (int na = 0; na < 4; na++) {
                int n = n0 + na * 16 + lr;
                u16 hv = f2bf(acc[ma][na][r] + bias);
                if (m < 64)
                    qT[((size_t)b * N_ + n) * D_ + m] = hv;
                else if (m < 128)
                    kT[((size_t)b * N_ + n) * D_ + (m - 64)] = hv;
                else
                    v[((size_t)b * C_ + (m - 128)) * (size_t)N_ + n] = hv;
            }
        }
    }
}

// ---------------- fused attention: full-j, c-split x2, small accumulator ----------------
// Grid 512 = (b, c-half, 64-i-tile); 8 waves of 64; wave owns 64i x 32c (acc = 32 f32).
// Total unified regs ~85 <= 128 -> 2 blocks/CU co-resident (4 waves/SIMD) WITHOUT
// spills (R9: 128-exact total -> spilled; R8: 152 -> 1 block; R7/R9: <=128 -> 45% occ).
// S phase (wave's 16-j slice of the 128-j tile) is duplicated across the 2 c-half
// blocks: +8.6 GF MFMA + ~3us exp -- cheap vs residency. Full j-range per block ->
// direct normalized output + residual (no partial-O pass, no reduce kernel).
__global__ __launch_bounds__(512, 4) void attn(const u16* __restrict__ qT, const u16* __restrict__ kT,
                                               const u16* __restrict__ v, const float* __restrict__ x,
                                               const float* __restrict__ gamma_p, float* __restrict__ out) {
    int w = blockIdx.x;                 // [0,512)
    int xcd = w & 7, slot = w >> 3;     // slot in [0,64)
    int b = xcd >> 1;                   // XCD holds one (b, c-half): V-half 2MB + K 512KB in L2
    int c0 = (xcd & 1) * 256;
    int i0 = slot * 64;

    int wv = threadIdx.x >> 6, lane = threadIdx.x & 63;
    int lr = lane & 15, lc = lane >> 4;

    __shared__ u16 P_lds[2][64 * 128];  // 2 x 16KB, swizzled: byte = i*256 + (jb ^ ((i&7)<<4))
    __shared__ u16 Q_lds[64 * 64];      // 8KB, swizzled: byte = i*128 + (db ^ ((i&7)<<4))
    __shared__ float s_l[64][8];        // per-wave partial row sums

    const u16* qTb = qT + (size_t)b * N_ * D_;
    const u16* kTb = kT + (size_t)b * N_ * D_;
    const u16* vb  = v  + (size_t)b * C_ * N_;
    char* Qc = reinterpret_cast<char*>(Q_lds);

    // ---- stage Q (64i x 64d) into swizzled LDS, once ----
    {
        int i = threadIdx.x >> 3, ch = threadIdx.x & 7;
        short8 qv = *reinterpret_cast<const short8*>(&qTb[(size_t)(i0 + i) * D_ + ch * 8]);
        int byte_off = i * 128 + ((ch * 16) ^ ((i & 7) << 4));
        *reinterpret_cast<short8*>(Qc + byte_off) = qv;
    }

    f32x4 acc[4][2] = {};               // [mt][ct]: O slice 64 i x 32 c (unnormalized)
    float lsum[4] = {0.f, 0.f, 0.f, 0.f};

    __syncthreads();

    for (int jt = 0; jt < 32; jt++) {
        char* pb = reinterpret_cast<char*>(P_lds[jt & 1]);

        // ---- K for this tile (single-buffer; stalls hidden by co-resident block) ----
        const u16* kp = kTb + (size_t)(jt * 128 + wv * 16 + lr) * D_;
        short8 kf0 = *reinterpret_cast<const short8*>(kp + lc * 8);
        short8 kf1 = *reinterpret_cast<const short8*>(kp + 32 + lc * 8);

        // ---- S phase: swapped mfma(K,Q): lane holds S'[i=mt*16+lr][j=wv*16+lc*4+r] ----
#pragma unroll
        for (int mt = 0; mt < 4; mt++) {
            int i = mt * 16 + lr;
            int qswz = (i & 7) << 4;
            short8 qf0 = *reinterpret_cast<const short8*>(Qc + i * 128 + ((lc * 16) ^ qswz));
            short8 qf1 = *reinterpret_cast<const short8*>(Qc + i * 128 + ((64 + lc * 16) ^ qswz));
            f32x4 s = {};
            s = MFMA16(kf0, qf0, s);
            s = MFMA16(kf1, qf1, s);
            s16x4 pk;
            float ps = 0.f;
#pragma unroll
            for (int r = 0; r < 4; r++) {
                float p = __builtin_amdgcn_exp2f(s[r]);   // exp(q.k): log2e folded into Wq
                ps += p;
                pk[r] = (short)f2bf(p);
            }
            lsum[mt] += ps;
            int byte_off = i * 256 + ((wv * 32 + lc * 8) ^ ((i & 7) << 4));
            *reinterpret_cast<s16x4*>(pb + byte_off) = pk;
        }

        // ---- barrier WITHOUT vmcnt drain: drain own LDS ops, then raw barrier ----
        asm volatile("s_waitcnt lgkmcnt(0)" ::: "memory");
        __builtin_amdgcn_s_barrier();
        __builtin_amdgcn_sched_barrier(0);

        // ---- PV phase: O[64 i][32 c] += P[64][128] * V[c][128 j]; V streamed at use ----
        __builtin_amdgcn_s_setprio(1);
#pragma unroll
        for (int kt = 0; kt < 4; kt++) {
            short8 pf[4];
#pragma unroll
            for (int mt = 0; mt < 4; mt++) {
                int i = mt * 16 + lr;
                int byte_off = i * 256 + (((kt * 64) + lc * 16) ^ ((i & 7) << 4));
                pf[mt] = *reinterpret_cast<const short8*>(pb + byte_off);
            }
#pragma unroll
            for (int ct = 0; ct < 2; ct++) {
                short8 vf = *reinterpret_cast<const short8*>(
                    &vb[(size_t)(c0 + wv * 32 + ct * 16 + lr) * N_ + jt * 128 + kt * 32 + lc * 8]);
#pragma unroll
                for (int mt = 0; mt < 4; mt++)
                    acc[mt][ct] = MFMA16(pf[mt], vf, acc[mt][ct]);
            }
        }
        __builtin_amdgcn_s_setprio(0);
    }

    // ---- row-sum reduce across lanes, then waves -> s_l ----
#pragma unroll
    for (int mt = 0; mt < 4; mt++) {
        float l_ = lsum[mt];
        l_ += __shfl_xor(l_, 16);
        l_ += __shfl_xor(l_, 32);
        if (lc == 0) s_l[mt * 16 + lr][wv] = l_;
    }
    __syncthreads();

    // ---- epilogue: out = gamma * (O / l) + x (direct, full j-range per block) ----
    float g = gamma_p[0];
    const float* xb = x + (size_t)b * C_ * N_;
    float* ob = out + (size_t)b * C_ * N_;
#pragma unroll
    for (int mt = 0; mt < 4; mt++) {
        float linv[4];
#pragma unroll
        for (int r = 0; r < 4; r++) {
            int i = mt * 16 + lc * 4 + r;
            float4 l0 = *reinterpret_cast<const float4*>(&s_l[i][0]);
            float4 l1 = *reinterpret_cast<const float4*>(&s_l[i][4]);
            linv[r] = 1.0f / (l0.x + l0.y + l0.z + l0.w + l1.x + l1.y + l1.z + l1.w);
        }
#pragma unroll
        for (int ct = 0; ct < 2; ct++) {
            int c = c0 + wv * 32 + ct * 16 + lr;
            size_t off = (size_t)c * N_ + i0 + mt * 16 + lc * 4;
            float4 xv = *reinterpret_cast<const float4*>(&xb[off]);
            float4 ov;
            ov.x = g * acc[mt][ct][0] * linv[0] + xv.x;
            ov.y = g * acc[mt][ct][1] * linv[1] + xv.y;
            ov.z = g * acc[mt][ct][2] * linv[2] + xv.z;
            ov.w = g * acc[mt][ct][3] * linv[3] + xv.w;
            *reinterpret_cast<float4*>(&ob[off]) = ov;
        }
    }
}

extern "C" void kernel_launch(void* const* d_in, const int* in_sizes, int n_in,
                              void* d_out, int out_size, void* d_ws, size_t ws_size,
                              hipStream_t stream) {
    const float* x     = (const float*)d_in[0];
    const float* Wq    = (const float*)d_in[1];
    const float* bq    = (const float*)d_in[2];
    const float* Wk    = (const float*)d_in[3];
    const float* bk    = (const float*)d_in[4];
    const float* Wv    = (const float*)d_in[5];
    const float* bv    = (const float*)d_in[6];
    const float* gamma = (const float*)d_in[7];
    float* out = (float*)d_out;

    char* ws = (char*)d_ws;
    // layout (bytes): xT 16MB | Wcat 640KB | biascat 4KB | qT 2MB | kT 2MB | v 16MB
    u16*   xT      = (u16*)ws;
    u16*   Wcat    = (u16*)(ws + (size_t)16777216);
    float* biascat = (float*)(ws + (size_t)16777216 + 655360);
    u16*   qT      = (u16*)(ws + (size_t)16777216 + 655360 + 4096);
    u16*   kT      = qT + (size_t)B_ * N_ * D_;
    u16*   v       = kT + (size_t)B_ * N_ * D_;

    prep_w<<<1280, 256, 0, stream>>>(Wq, bq, Wk, bk, Wv, bv, Wcat, biascat);
    transpose_x<<<dim3(N_ / 32, C_ / 32, B_), 256, 0, stream>>>(x, xT);
    proj_gemm<<<dim3(N_ / 256, 640 / 64, B_), 256, 0, stream>>>(Wcat, biascat, xT, qT, kT, v);
    attn<<<512, 512, 0, stream>>>(qT, kT, v, x, gamma, out);
}